// Round 1
// baseline (1379.104 us; speedup 1.0000x reference)
//
#include <hip/hip_runtime.h>
#include <math.h>

#define H_DIM 7168
#define N_EXP 256
#define N_GRP 8
#define G_SZ  32
#define TOPK_G 4
#define TOPK   8
#define BM 64
#define BK 32
#define AS_STRIDE 68    // 64 + 4 pad, keeps float4 rows 16B-aligned
#define WS_STRIDE 260   // 256 + 4 pad, 16B-aligned
#define SC_STRIDE 257   // scalar access, stride%32==1 -> conflict-free row scans
#define SMEM_FLOATS (BK*AS_STRIDE + BK*WS_STRIDE)   // 10496 floats = 41984 B

__global__ __launch_bounds__(256)
void moe_gate_kernel(const float* __restrict__ A,    // [S, H]
                     const float* __restrict__ W,    // [E, H]
                     const float* __restrict__ bias, // [E]
                     float* __restrict__ out,        // [S*8 weights | S*8 idx-as-float]
                     int S)
{
    __shared__ float smem[SMEM_FLOATS];
    __shared__ float bias_s[N_EXP];

    float* As = smem;                    // [BK][AS_STRIDE], transposed A tile
    float* Ws = smem + BK * AS_STRIDE;   // [BK][WS_STRIDE], transposed W tile

    const int tid  = threadIdx.x;
    const int tc   = tid & 31;   // 32 column-groups
    const int tr   = tid >> 5;   // 8 row-groups
    const int brow = blockIdx.x * BM;

    bias_s[tid & (N_EXP - 1)] = bias[tid & (N_EXP - 1)];

    float acc[8][8];
    #pragma unroll
    for (int i = 0; i < 8; ++i)
        #pragma unroll
        for (int j = 0; j < 8; ++j) acc[i][j] = 0.0f;

    // thread's rows: { tr*4+i, 32+tr*4+i }, cols: { tc*4+j, 128+tc*4+j }
    for (int k0 = 0; k0 < H_DIM; k0 += BK) {
        // stage A tile: 64 rows x 32 k  (512 float4, 2 per thread)
        #pragma unroll
        for (int i = 0; i < 2; ++i) {
            int fidx = i * 256 + tid;
            int r = fidx >> 3, q = fidx & 7;
            float4 v = *reinterpret_cast<const float4*>(
                A + (size_t)(brow + r) * H_DIM + k0 + q * 4);
            As[(q*4+0)*AS_STRIDE + r] = v.x;
            As[(q*4+1)*AS_STRIDE + r] = v.y;
            As[(q*4+2)*AS_STRIDE + r] = v.z;
            As[(q*4+3)*AS_STRIDE + r] = v.w;
        }
        // stage W tile: 256 experts x 32 k (2048 float4, 8 per thread)
        #pragma unroll
        for (int i = 0; i < 8; ++i) {
            int fidx = i * 256 + tid;
            int e = fidx >> 3, q = fidx & 7;
            float4 v = *reinterpret_cast<const float4*>(
                W + (size_t)e * H_DIM + k0 + q * 4);
            Ws[(q*4+0)*WS_STRIDE + e] = v.x;
            Ws[(q*4+1)*WS_STRIDE + e] = v.y;
            Ws[(q*4+2)*WS_STRIDE + e] = v.z;
            Ws[(q*4+3)*WS_STRIDE + e] = v.w;
        }
        __syncthreads();

        #pragma unroll 8
        for (int k = 0; k < BK; ++k) {
            const float4 a0 = *reinterpret_cast<const float4*>(As + k*AS_STRIDE + tr*4);
            const float4 a1 = *reinterpret_cast<const float4*>(As + k*AS_STRIDE + 32 + tr*4);
            const float4 b0 = *reinterpret_cast<const float4*>(Ws + k*WS_STRIDE + tc*4);
            const float4 b1 = *reinterpret_cast<const float4*>(Ws + k*WS_STRIDE + 128 + tc*4);
            float av[8] = {a0.x,a0.y,a0.z,a0.w,a1.x,a1.y,a1.z,a1.w};
            float bv[8] = {b0.x,b0.y,b0.z,b0.w,b1.x,b1.y,b1.z,b1.w};
            #pragma unroll
            for (int i = 0; i < 8; ++i)
                #pragma unroll
                for (int j = 0; j < 8; ++j)
                    acc[i][j] = fmaf(av[i], bv[j], acc[i][j]);
        }
        __syncthreads();
    }

    // ---- epilogue: sigmoid -> LDS scores, then per-row gating ----
    // Two passes of 32 rows each so the score buffer (32 x 257 floats) fits
    // in the same LDS as the GEMM tiles.
    float* Sc = smem;
    #pragma unroll
    for (int p = 0; p < 2; ++p) {
        #pragma unroll
        for (int i = 0; i < 4; ++i) {
            int rl = tr * 4 + i;   // local row 0..31 within this pass
            #pragma unroll
            for (int j = 0; j < 8; ++j) {
                int c = (j < 4) ? (tc * 4 + j) : (128 + tc * 4 + (j - 4));
                float x = acc[p * 4 + i][j];
                Sc[rl * SC_STRIDE + c] = 1.0f / (1.0f + expf(-x));
            }
        }
        __syncthreads();

        if (tid < 32) {
            const float* s = Sc + tid * SC_STRIDE;
            const int row = brow + p * 32 + tid;

            // group scores = sum of top-2 biased scores in each group of 32
            float gs[N_GRP];
            #pragma unroll
            for (int g = 0; g < N_GRP; ++g) {
                float m1 = -1e30f, m2 = -1e30f;
                for (int j = 0; j < G_SZ; ++j) {
                    float v = s[g * G_SZ + j] + bias_s[g * G_SZ + j];
                    if (v > m1) { m2 = m1; m1 = v; }
                    else if (v > m2) { m2 = v; }
                }
                gs[g] = m1 + m2;
            }

            // top-4 groups (strict > scan: ties -> lowest index, matches lax.top_k)
            unsigned gmask = 0;
            #pragma unroll
            for (int t = 0; t < TOPK_G; ++t) {
                float best = -1e30f; int bi = 0;
                #pragma unroll
                for (int g = 0; g < N_GRP; ++g) {
                    bool avail = !((gmask >> g) & 1);
                    if (avail && gs[g] > best) { best = gs[g]; bi = g; }
                }
                gmask |= 1u << bi;
            }

            // top-8 experts over tmp = selected_group ? (s+bias) : 0.0
            unsigned long long ch0 = 0, ch1 = 0, ch2 = 0, ch3 = 0;
            float wv[TOPK]; int wi[TOPK];
            float wsum = 0.0f;
            #pragma unroll
            for (int t = 0; t < TOPK; ++t) {
                float best = -1e30f; int bi = 0;
                for (int e = 0; e < N_EXP; ++e) {
                    bool sel = (gmask >> (e >> 5)) & 1;
                    float v = sel ? (s[e] + bias_s[e]) : 0.0f;
                    unsigned long long cm = (e < 64) ? ch0 : (e < 128) ? ch1
                                           : (e < 192) ? ch2 : ch3;
                    bool taken = (cm >> (e & 63)) & 1;
                    if (!taken && v > best) { best = v; bi = e; }
                }
                if      (bi < 64)  ch0 |= 1ull << bi;
                else if (bi < 128) ch1 |= 1ull << (bi - 64);
                else if (bi < 192) ch2 |= 1ull << (bi - 128);
                else               ch3 |= 1ull << (bi - 192);
                wi[t] = bi;
                float sv = s[bi];   // UNBIASED score for the weight
                wv[t] = sv;
                wsum += sv;
            }

            float scale = 2.5f / (wsum + 1e-20f);
            #pragma unroll
            for (int t = 0; t < TOPK; ++t) {
                out[(size_t)row * TOPK + t] = wv[t] * scale;
                out[(size_t)S * TOPK + (size_t)row * TOPK + t] = (float)wi[t];
            }
        }
        __syncthreads();
    }
}

extern "C" void kernel_launch(void* const* d_in, const int* in_sizes, int n_in,
                              void* d_out, int out_size, void* d_ws, size_t ws_size,
                              hipStream_t stream) {
    const float* A    = (const float*)d_in[0];
    const float* W    = (const float*)d_in[1];
    const float* bias = (const float*)d_in[2];
    float* out = (float*)d_out;
    const int S = in_sizes[0] / H_DIM;   // 16384

    dim3 grid(S / BM), block(256);
    moe_gate_kernel<<<grid, block, 0, stream>>>(A, W, bias, out, S);
}

// Round 3
// 575.654 us; speedup vs baseline: 2.3957x; 2.3957x over previous
//
#include <hip/hip_runtime.h>
#include <math.h>

#define H_DIM 7168
#define N_EXP 256
#define N_GRP 8
#define G_SZ  32
#define TOPK_G 4
#define TOPK   8
#define BM 32
#define BK 32
#define NTILES (H_DIM / BK)          // 224
#define TILE_W_BYTES 32768           // per k-tile: W_hi(16KB) + W_lo(16KB)
#define WS_NEEDED ((size_t)NTILES * TILE_W_BYTES)   // 7,340,032 B

// Exponent pre-scaling keeps all fp16 lo-terms in normal range (exact pow2).
#define SA_SCALE 256.0f              // A * 2^8
#define SW_SCALE 4096.0f             // W * 2^12
#define DESCALE  (1.0f / 1048576.0f) // 2^-20

// LDS buffer layout (per buffer, 36 KB):
//   [0,2048)      A_hi  [32 rows][32 k] fp16, XOR-swizzled
//   [2048,4096)   A_lo
//   [4096,20480)  W_hi  [256 e][32 k] fp16, XOR-swizzled
//   [20480,36864) W_lo
#define BUF_BYTES 36864
#define A_HI 0
#define A_LO 2048
#define W_HI 4096
#define W_LO 20480

typedef __attribute__((ext_vector_type(8))) _Float16 f16x8;
typedef __attribute__((ext_vector_type(4))) float f32x4;
typedef __attribute__((ext_vector_type(4))) unsigned short u16x4;

__device__ inline void split2h(float x, unsigned short& h, unsigned short& l) {
    _Float16 hf = (_Float16)x;                 // v_cvt_f16_f32, RNE
    _Float16 lf = (_Float16)(x - (float)hf);   // x - hf exact (Sterbenz)
    h = __builtin_bit_cast(unsigned short, hf);
    l = __builtin_bit_cast(unsigned short, lf);
}

// ---- pre-kernel: fp32 W -> pre-swizzled fp16 hi/lo k-tile images in ws ----
__global__ __launch_bounds__(256)
void convert_w_kernel(const float* __restrict__ W, char* __restrict__ ws) {
    int idx = blockIdx.x * 256 + threadIdx.x;     // [0, 256*7168/2)
    int e   = idx / (H_DIM / 2);
    int kp  = idx - e * (H_DIM / 2);
    int k   = kp * 2;
    int t   = k >> 5;
    int kk  = k & 31;
    float x0 = W[(size_t)e * H_DIM + k]     * SW_SCALE;
    float x1 = W[(size_t)e * H_DIM + k + 1] * SW_SCALE;
    unsigned short h0, l0, h1, l1;
    split2h(x0, h0, l0);
    split2h(x1, h1, l1);
    int off = ((e << 6) + (kk << 1)) ^ ((e & 7) << 4);  // 4B-aligned (kk even)
    char* base = ws + (size_t)t * TILE_W_BYTES;
    *(unsigned int*)(base + off)         = ((unsigned)h1 << 16) | h0;
    *(unsigned int*)(base + 16384 + off) = ((unsigned)l1 << 16) | l0;
}

template<int USE_WS>
__global__ __launch_bounds__(256, 2)
void moe_gate_mfma(const float* __restrict__ A,
                   const float* __restrict__ W,
                   const char*  __restrict__ ws,
                   const float* __restrict__ bias,
                   float* __restrict__ out, int S)
{
    __shared__ __align__(128) char smem[2 * BUF_BYTES];
    __shared__ float bias_s[N_EXP];

    const int tid  = threadIdx.x;
    const int lane = tid & 63;
    const int wave = tid >> 6;
    const int brow = blockIdx.x * BM;

    bias_s[tid & (N_EXP - 1)] = bias[tid & (N_EXP - 1)];

    // fragment read offset: row/expert = lane&15, k-chunk byte = (lane>>4)*16
    const int fr   = lane & 15;
    const int fkb  = (lane >> 4) << 4;
    const int foff = ((fr << 6) + fkb) ^ ((fr & 7) << 4);

    // A staging decomposition: thread -> (row, float4-chunk)
    const int ar   = tid >> 3;      // 0..31
    const int akq  = tid & 7;       // 0..7
    const int aoff = ((ar << 6) + (akq << 3)) ^ ((ar & 7) << 4);
    const float* Aptr = A + (size_t)(brow + ar) * H_DIM + (akq << 2);

    f32x4 acc[2][4] = {};

    auto stageW_ws = [&](int t, char* buf) {
        const char* src = ws + (size_t)t * TILE_W_BYTES + tid * 16;
        #pragma unroll
        for (int c = 0; c < 4; ++c) {
            __builtin_amdgcn_global_load_lds(
                (const __attribute__((address_space(1))) void*)(src + c * 4096),
                (__attribute__((address_space(3))) void*)(buf + W_HI + c * 4096 + tid * 16),
                16, 0, 0);
            __builtin_amdgcn_global_load_lds(
                (const __attribute__((address_space(1))) void*)(src + 16384 + c * 4096),
                (__attribute__((address_space(3))) void*)(buf + W_LO + c * 4096 + tid * 16),
                16, 0, 0);
        }
    };

    auto writeA = [&](const float4& v, char* buf) {
        unsigned short h0,h1,h2,h3, l0,l1,l2,l3;
        split2h(v.x * SA_SCALE, h0, l0); split2h(v.y * SA_SCALE, h1, l1);
        split2h(v.z * SA_SCALE, h2, l2); split2h(v.w * SA_SCALE, h3, l3);
        *(u16x4*)(buf + A_HI + aoff) = u16x4{h0, h1, h2, h3};
        *(u16x4*)(buf + A_LO + aoff) = u16x4{l0, l1, l2, l3};
    };

    auto writeW_conv = [&](const float4* wv, char* buf) {
        #pragma unroll
        for (int c = 0; c < 8; ++c) {
            int fidx = c * 256 + tid;
            int e = fidx >> 3, kq = fidx & 7;
            unsigned short h0,h1,h2,h3, l0,l1,l2,l3;
            split2h(wv[c].x * SW_SCALE, h0, l0); split2h(wv[c].y * SW_SCALE, h1, l1);
            split2h(wv[c].z * SW_SCALE, h2, l2); split2h(wv[c].w * SW_SCALE, h3, l3);
            int off = ((e << 6) + (kq << 3)) ^ ((e & 7) << 4);
            *(u16x4*)(buf + W_HI + off) = u16x4{h0, h1, h2, h3};
            *(u16x4*)(buf + W_LO + off) = u16x4{l0, l1, l2, l3};
        }
    };

    auto compute = [&](const char* buf) {
        f16x8 ah0 = *(const f16x8*)(buf + A_HI + 0    + foff);
        f16x8 ah1 = *(const f16x8*)(buf + A_HI + 1024 + foff);
        f16x8 al0 = *(const f16x8*)(buf + A_LO + 0    + foff);
        f16x8 al1 = *(const f16x8*)(buf + A_LO + 1024 + foff);
        const char* wb = buf + (wave << 12);
        #pragma unroll
        for (int nj = 0; nj < 4; ++nj) {
            f16x8 bh = *(const f16x8*)(wb + W_HI + nj * 1024 + foff);
            f16x8 bl = *(const f16x8*)(wb + W_LO + nj * 1024 + foff);
            acc[0][nj] = __builtin_amdgcn_mfma_f32_16x16x32_f16(ah0, bh, acc[0][nj], 0, 0, 0);
            acc[1][nj] = __builtin_amdgcn_mfma_f32_16x16x32_f16(ah1, bh, acc[1][nj], 0, 0, 0);
            acc[0][nj] = __builtin_amdgcn_mfma_f32_16x16x32_f16(al0, bh, acc[0][nj], 0, 0, 0);
            acc[1][nj] = __builtin_amdgcn_mfma_f32_16x16x32_f16(al1, bh, acc[1][nj], 0, 0, 0);
            acc[0][nj] = __builtin_amdgcn_mfma_f32_16x16x32_f16(ah0, bl, acc[0][nj], 0, 0, 0);
            acc[1][nj] = __builtin_amdgcn_mfma_f32_16x16x32_f16(ah1, bl, acc[1][nj], 0, 0, 0);
        }
    };

    // ---- prologue: stage tile 0 ----
    {
        char* b0 = smem;
        float4 av = *(const float4*)Aptr;
        if (USE_WS) {
            stageW_ws(0, b0);
        } else {
            float4 wv[8];
            #pragma unroll
            for (int c = 0; c < 8; ++c) {
                int fidx = c * 256 + tid;
                int e = fidx >> 3, kq = fidx & 7;
                wv[c] = *(const float4*)(W + (size_t)e * H_DIM + (kq << 2));
            }
            writeW_conv(wv, b0);
        }
        writeA(av, b0);
    }
    __syncthreads();

    // ---- main K loop, double-buffered ----
    int buf = 0;
    for (int t = 0; t < NTILES; ++t) {
        char* cur = smem + buf * BUF_BYTES;
        char* nxt = smem + (buf ^ 1) * BUF_BYTES;
        const bool pf = (t + 1 < NTILES);
        float4 av;
        float4 wv[8];
        if (pf) {
            av = *(const float4*)(Aptr + (size_t)(t + 1) * BK);
            if (USE_WS) {
                stageW_ws(t + 1, nxt);
            } else {
                #pragma unroll
                for (int c = 0; c < 8; ++c) {
                    int fidx = c * 256 + tid;
                    int e = fidx >> 3, kq = fidx & 7;
                    wv[c] = *(const float4*)(W + (size_t)e * H_DIM + (t + 1) * BK + (kq << 2));
                }
            }
        }
        compute(cur);
        if (pf) {
            writeA(av, nxt);
            if (!USE_WS) writeW_conv(wv, nxt);
        }
        __syncthreads();
        buf ^= 1;
    }

    // ---- epilogue: descale -> sigmoid -> LDS scores ----
    float* Sc = (float*)smem;   // [32][257], 32.9 KB, reuses GEMM buffers
    #pragma unroll
    for (int mi = 0; mi < 2; ++mi)
        #pragma unroll
        for (int nj = 0; nj < 4; ++nj)
            #pragma unroll
            for (int q = 0; q < 4; ++q) {
                int row = mi * 16 + ((lane >> 4) << 2) + q;
                int col = (wave << 6) + (nj << 4) + (lane & 15);
                float x = acc[mi][nj][q] * DESCALE;
                Sc[row * 257 + col] = 1.0f / (1.0f + expf(-x));
            }
    __syncthreads();

    // ---- per-row gating (proven R1 logic) ----
    if (tid < 32) {
        const float* s = Sc + tid * 257;
        const int row = brow + tid;

        float gs[N_GRP];
        #pragma unroll
        for (int g = 0; g < N_GRP; ++g) {
            float m1 = -1e30f, m2 = -1e30f;
            for (int j = 0; j < G_SZ; ++j) {
                float v = s[g * G_SZ + j] + bias_s[g * G_SZ + j];
                if (v > m1) { m2 = m1; m1 = v; }
                else if (v > m2) { m2 = v; }
            }
            gs[g] = m1 + m2;
        }

        unsigned gmask = 0;
        #pragma unroll
        for (int t = 0; t < TOPK_G; ++t) {
            float best = -1e30f; int bi = 0;
            #pragma unroll
            for (int g = 0; g < N_GRP; ++g) {
                bool avail = !((gmask >> g) & 1);
                if (avail && gs[g] > best) { best = gs[g]; bi = g; }
            }
            gmask |= 1u << bi;
        }

        unsigned long long ch0 = 0, ch1 = 0, ch2 = 0, ch3 = 0;
        float wv[TOPK]; int wi[TOPK];
        float wsum = 0.0f;
        #pragma unroll
        for (int t = 0; t < TOPK; ++t) {
            float best = -1e30f; int bi = 0;
            for (int e = 0; e < N_EXP; ++e) {
                bool sel = (gmask >> (e >> 5)) & 1;
                float v = sel ? (s[e] + bias_s[e]) : 0.0f;
                unsigned long long cm = (e < 64) ? ch0 : (e < 128) ? ch1
                                       : (e < 192) ? ch2 : ch3;
                bool taken = (cm >> (e & 63)) & 1;
                if (!taken && v > best) { best = v; bi = e; }
            }
            if      (bi < 64)  ch0 |= 1ull << bi;
            else if (bi < 128) ch1 |= 1ull << (bi - 64);
            else if (bi < 192) ch2 |= 1ull << (bi - 128);
            else               ch3 |= 1ull << (bi - 192);
            wi[t] = bi;
            float sv = s[bi];
            wv[t] = sv;
            wsum += sv;
        }

        float scale = 2.5f / (wsum + 1e-20f);
        #pragma unroll
        for (int t = 0; t < TOPK; ++t) {
            out[(size_t)row * TOPK + t] = wv[t] * scale;
            out[(size_t)S * TOPK + (size_t)row * TOPK + t] = (float)wi[t];
        }
    }
}

extern "C" void kernel_launch(void* const* d_in, const int* in_sizes, int n_in,
                              void* d_out, int out_size, void* d_ws, size_t ws_size,
                              hipStream_t stream) {
    const float* A    = (const float*)d_in[0];
    const float* W    = (const float*)d_in[1];
    const float* bias = (const float*)d_in[2];
    float* out = (float*)d_out;
    const int S = in_sizes[0] / H_DIM;   // 16384

    if (ws_size >= WS_NEEDED) {
        convert_w_kernel<<<dim3((N_EXP * (H_DIM / 2)) / 256), 256, 0, stream>>>(
            W, (char*)d_ws);
        moe_gate_mfma<1><<<dim3(S / BM), 256, 0, stream>>>(
            A, W, (const char*)d_ws, bias, out, S);
    } else {
        moe_gate_mfma<0><<<dim3(S / BM), 256, 0, stream>>>(
            A, W, nullptr, bias, out, S);
    }
}

// Round 5
// 389.496 us; speedup vs baseline: 3.5407x; 1.4779x over previous
//
#include <hip/hip_runtime.h>
#include <math.h>

#define H_DIM 7168
#define N_EXP 256
#define N_GRP 8
#define G_SZ  32
#define TOPK_G 4
#define TOPK   8
#define BM 64
#define BK 32
#define NTILES (H_DIM / BK)          // 224
#define TILE_W_BYTES 32768           // per k-tile: W_hi(16KB) | W_lo(16KB)

#define SA_SCALE 256.0f              // A * 2^8   (exact pow2)
#define SW_SCALE 4096.0f             // W * 2^12  (exact pow2)
#define DESCALE  (1.0f / 1048576.0f) // 2^-20

// GEMM LDS: 3 W buffers + 2 A buffers
//   wbuf[i] = smem + i*32768   (hi 16KB | lo 16KB), i=0..2
//   abuf[j] = smem + 98304 + j*8192 (hi 4KB | lo 4KB), j=0..1
// Epilogue overlay: Sc f32[64][257] @0, Sb f32[64][257] @66560, bias @132352
#define SMEM_BYTES 133376
#define ABUF_BASE 98304

__device__ __align__(256) char g_wimg[(size_t)NTILES * TILE_W_BYTES];

typedef __attribute__((ext_vector_type(8))) _Float16 f16x8;
typedef __attribute__((ext_vector_type(4))) float f32x4;
typedef __attribute__((ext_vector_type(8))) unsigned short u16x8;

__device__ inline void split2h(float x, unsigned short& h, unsigned short& l) {
    _Float16 hf = (_Float16)x;                 // RNE
    _Float16 lf = (_Float16)(x - (float)hf);   // exact residual
    h = __builtin_bit_cast(unsigned short, hf);
    l = __builtin_bit_cast(unsigned short, lf);
}

// ---- pre-kernel: fp32 W -> pre-swizzled fp16 hi/lo k-tile images (verbatim R3) ----
__global__ __launch_bounds__(256)
void convert_w_kernel(const float* __restrict__ W) {
    int idx = blockIdx.x * 256 + threadIdx.x;     // [0, 256*3584)
    int e   = idx / (H_DIM / 2);
    int kp  = idx - e * (H_DIM / 2);
    int k   = kp * 2;
    int t   = k >> 5;
    int kk  = k & 31;
    float x0 = W[(size_t)e * H_DIM + k]     * SW_SCALE;
    float x1 = W[(size_t)e * H_DIM + k + 1] * SW_SCALE;
    unsigned short h0, l0, h1, l1;
    split2h(x0, h0, l0);
    split2h(x1, h1, l1);
    int off = ((e << 6) + (kk << 1)) ^ ((e & 7) << 4);
    char* base = g_wimg + (size_t)t * TILE_W_BYTES;
    *(unsigned int*)(base + off)         = ((unsigned)h1 << 16) | h0;
    *(unsigned int*)(base + 16384 + off) = ((unsigned)l1 << 16) | l0;
}

__global__ __launch_bounds__(512, 1)
void moe_gate_mfma(const float* __restrict__ A,
                   const float* __restrict__ bias,
                   float* __restrict__ out, int S)
{
    __shared__ __align__(128) char smem[SMEM_BYTES];

    const int tid  = threadIdx.x;
    const int lane = tid & 63;
    const int wave = tid >> 6;          // 0..7, owns experts [wave*32, wave*32+32)
    const int brow = blockIdx.x * BM;

    // fragment read offset (both A and W images share this swizzle form)
    const int fr   = lane & 15;
    const int fkb  = (lane >> 4) << 4;
    const int fswz = ((fr << 6) + fkb) ^ ((fr & 7) << 4);

    // A staging: thread (tid<256) -> row r = tid>>2 (0..63), 16B k-chunk c = tid&3
    const int ar   = (tid >> 2) & 63;
    const int ac   = tid & 3;
    const int aswz = ((ar << 6) + (ac << 4)) ^ ((ar & 7) << 4);
    // float4-typed base: per k-tile stride = BK floats = 8 float4
    const float4* Ag4 = reinterpret_cast<const float4*>(
        A + (size_t)(brow + ar) * H_DIM + (ac << 3));

    f32x4 acc[4][2] = {};

    auto stageW = [&](int t, char* buf) {
        const char* src = g_wimg + (size_t)t * TILE_W_BYTES + tid * 16;
        char* dst = buf + tid * 16;
        #pragma unroll
        for (int c = 0; c < 4; ++c)
            __builtin_amdgcn_global_load_lds(
                (const __attribute__((address_space(1))) void*)(src + c * 8192),
                (__attribute__((address_space(3))) void*)(dst + c * 8192),
                16, 0, 0);
    };

    auto writeA = [&](const float4& v0, const float4& v1, char* ab) {
        unsigned short h[8], l[8];
        split2h(v0.x * SA_SCALE, h[0], l[0]); split2h(v0.y * SA_SCALE, h[1], l[1]);
        split2h(v0.z * SA_SCALE, h[2], l[2]); split2h(v0.w * SA_SCALE, h[3], l[3]);
        split2h(v1.x * SA_SCALE, h[4], l[4]); split2h(v1.y * SA_SCALE, h[5], l[5]);
        split2h(v1.z * SA_SCALE, h[6], l[6]); split2h(v1.w * SA_SCALE, h[7], l[7]);
        *(u16x8*)(ab + aswz)        = u16x8{h[0],h[1],h[2],h[3],h[4],h[5],h[6],h[7]};
        *(u16x8*)(ab + 4096 + aswz) = u16x8{l[0],l[1],l[2],l[3],l[4],l[5],l[6],l[7]};
    };

    auto compute = [&](const char* wb, const char* ab) {
        f16x8 ah[4], al[4];
        #pragma unroll
        for (int mi = 0; mi < 4; ++mi) {
            ah[mi] = *(const f16x8*)(ab + mi * 1024 + fswz);
            al[mi] = *(const f16x8*)(ab + 4096 + mi * 1024 + fswz);
        }
        const char* wbase = wb + wave * 2048;
        #pragma unroll
        for (int nj = 0; nj < 2; ++nj) {
            f16x8 bh = *(const f16x8*)(wbase + nj * 1024 + fswz);
            f16x8 bl = *(const f16x8*)(wbase + 16384 + nj * 1024 + fswz);
            #pragma unroll
            for (int mi = 0; mi < 4; ++mi) {
                acc[mi][nj] = __builtin_amdgcn_mfma_f32_16x16x32_f16(ah[mi], bh, acc[mi][nj], 0, 0, 0);
                acc[mi][nj] = __builtin_amdgcn_mfma_f32_16x16x32_f16(al[mi], bh, acc[mi][nj], 0, 0, 0);
                acc[mi][nj] = __builtin_amdgcn_mfma_f32_16x16x32_f16(ah[mi], bl, acc[mi][nj], 0, 0, 0);
            }
        }
    };

    // ---- prologue: A(0) regs, stage W(0), W(1) ----
    {
        float4 a0, a1;
        if (tid < 256) { a0 = Ag4[0]; a1 = Ag4[1]; }      // k-tile 0
        stageW(0, smem);
        stageW(1, smem + 32768);
        if (tid < 256) writeA(a0, a1, smem + ABUF_BASE);
        asm volatile("s_waitcnt vmcnt(4) lgkmcnt(0)" ::: "memory");
        __builtin_amdgcn_s_barrier();
    }

    // ---- main K loop: 3-deep W pipeline, counted vmcnt ----
    for (int t = 0; t < NTILES; ++t) {
        const char* wb = smem + (t % 3) * 32768;
        const char* ab = smem + ABUF_BASE + (t & 1) * 8192;
        float4 a0, a1;
        const bool haveA = (t + 1 < NTILES) && (tid < 256);
        if (haveA) {
            const float4* p = Ag4 + (size_t)(t + 1) * (BK / 4);
            a0 = p[0]; a1 = p[1];
        }
        if (t + 2 < NTILES)
            stageW(t + 2, smem + ((t + 2) % 3) * 32768);
        compute(wb, ab);
        if (haveA)
            writeA(a0, a1, smem + ABUF_BASE + ((t + 1) & 1) * 8192);
        if (t + 2 < NTILES) {
            asm volatile("s_waitcnt vmcnt(4) lgkmcnt(0)" ::: "memory");
        } else {
            asm volatile("s_waitcnt vmcnt(0) lgkmcnt(0)" ::: "memory");
        }
        __builtin_amdgcn_s_barrier();
    }

    // ---- epilogue: descale -> sigmoid -> Sc / Sb(biased) in LDS ----
    float* Sc = (float*)smem;                     // [64][257]
    float* Sb = (float*)(smem + 66560);           // [64][257]
    #pragma unroll
    for (int mi = 0; mi < 4; ++mi)
        #pragma unroll
        for (int nj = 0; nj < 2; ++nj)
            #pragma unroll
            for (int q = 0; q < 4; ++q) {
                int row = mi * 16 + ((lane >> 4) << 2) + q;
                int col = wave * 32 + nj * 16 + (lane & 15);
                float x = acc[mi][nj][q] * DESCALE;
                float s = 1.0f / (1.0f + expf(-x));
                Sc[row * 257 + col] = s;
                Sb[row * 257 + col] = s + bias[col];
            }
    __syncthreads();

    // ---- per-row gating (R3-proven logic, 64 rows) ----
    if (tid < 64) {
        const float* s  = Sc + tid * 257;
        const float* sb = Sb + tid * 257;
        const int row = brow + tid;

        float gs[N_GRP];
        #pragma unroll
        for (int g = 0; g < N_GRP; ++g) {
            float m1 = -1e30f, m2 = -1e30f;
            for (int j = 0; j < G_SZ; ++j) {
                float v = sb[g * G_SZ + j];
                if (v > m1) { m2 = m1; m1 = v; }
                else if (v > m2) { m2 = v; }
            }
            gs[g] = m1 + m2;
        }

        unsigned gmask = 0;
        #pragma unroll
        for (int t = 0; t < TOPK_G; ++t) {
            float best = -1e30f; int bi = 0;
            #pragma unroll
            for (int g = 0; g < N_GRP; ++g) {
                bool avail = !((gmask >> g) & 1);
                if (avail && gs[g] > best) { best = gs[g]; bi = g; }
            }
            gmask |= 1u << bi;
        }

        unsigned long long ch0 = 0, ch1 = 0, ch2 = 0, ch3 = 0;
        float wv[TOPK]; int wi[TOPK];
        float wsum = 0.0f;
        #pragma unroll
        for (int t = 0; t < TOPK; ++t) {
            float best = -1e30f; int bi = 0;
            for (int e = 0; e < N_EXP; ++e) {
                bool sel = (gmask >> (e >> 5)) & 1;
                float v = sel ? sb[e] : 0.0f;
                unsigned long long cm = (e < 64) ? ch0 : (e < 128) ? ch1
                                       : (e < 192) ? ch2 : ch3;
                bool taken = (cm >> (e & 63)) & 1;
                if (!taken && v > best) { best = v; bi = e; }
            }
            if      (bi < 64)  ch0 |= 1ull << bi;
            else if (bi < 128) ch1 |= 1ull << (bi - 64);
            else if (bi < 192) ch2 |= 1ull << (bi - 128);
            else               ch3 |= 1ull << (bi - 192);
            wi[t] = bi;
            float sv = s[bi];
            wv[t] = sv;
            wsum += sv;
        }

        float scale = 2.5f / (wsum + 1e-20f);
        #pragma unroll
        for (int t = 0; t < TOPK; ++t) {
            out[(size_t)row * TOPK + t] = wv[t] * scale;
            out[(size_t)S * TOPK + (size_t)row * TOPK + t] = (float)wi[t];
        }
    }
}

extern "C" void kernel_launch(void* const* d_in, const int* in_sizes, int n_in,
                              void* d_out, int out_size, void* d_ws, size_t ws_size,
                              hipStream_t stream) {
    const float* A    = (const float*)d_in[0];
    const float* W    = (const float*)d_in[1];
    const float* bias = (const float*)d_in[2];
    float* out = (float*)d_out;
    const int S = in_sizes[0] / H_DIM;   // 16384

    convert_w_kernel<<<dim3((N_EXP * (H_DIM / 2)) / 256), 256, 0, stream>>>(W);
    moe_gate_mfma<<<dim3(S / BM), 512, 0, stream>>>(A, bias, out, S);
}